// Round 4
// baseline (445.446 us; speedup 1.0000x reference)
//
#include <hip/hip_runtime.h>

#define HH 512
#define WW 512
#define NB 4
#define NC 25              // final channel count: 1 + 12*2
#define HWs (HH * WW)

__device__ __forceinline__ int refl(int p, int n) {
    // jnp.pad mode='reflect' (no edge repeat); single reflection valid for |pad| < n
    p = (p < 0) ? -p : p;
    p = (p >= n) ? (2 * n - 2 - p) : p;
    return p;
}

__global__ __launch_bounds__(256) void copy_x_kernel(const float* __restrict__ x,
                                                     float* __restrict__ out) {
    int t = blockIdx.x * 256 + threadIdx.x;   // NB*HWs/4 = 262144 threads
    int b = t >> 16;                          // HWs/4 = 65536 float4 per batch
    int r = t & 65535;
    const float4* src = (const float4*)(x + (size_t)b * HWs);
    float4* dst = (float4*)(out + (size_t)b * NC * HWs);
    dst[r] = src[r];
}

// Block = 256 threads; tile = 512 cols x 4 rows, 2 out channels.
// Per channel: stage 12 full-width rows (3 kh-groups x 4 rows) into LDS via
// global_load_lds width-16 (1KB chunks, no VGPR roundtrip), plus a 2*DIL
// reflected column halo per row (scalar). Double-buffered, 1 barrier/channel.
// Compute: each thread owns 4 horizontal px x 2 row-passes;每 tap group is a
// contiguous float4 LDS read (wide ds_read), all bytes used.
template <int NIN, int DIL>
__global__ __launch_bounds__(256) void msd_layer(const float* __restrict__ wts,
                                                 const float* __restrict__ bias,
                                                 float* __restrict__ buf,
                                                 int layer) {
    constexpr int SEGP = ((512 + 2 * DIL + 3) / 4) * 4;  // padded row length (floats)
    constexpr int NR = 12;                               // staged rows per channel
    constexpr int NHAL = (24 * DIL + 255) / 256;         // halo iters per thread

    __shared__ __align__(16) float lds[2][NR * SEGP];

    const int tid = threadIdx.x;
    const int lane = tid & 63;
    const int wv = __builtin_amdgcn_readfirstlane(tid >> 6);   // wave id 0..3
    const int blk = blockIdx.x;
    const int b = blk >> 7;            // image
    const int h = (blk & 127) << 2;    // output rows h..h+3
    const int w0 = (tid & 127) << 2;   // 4-px column group
    const int jbase = tid >> 7;        // row-pass base (0/1)

    const float* base = buf + (size_t)b * NC * HWs;

    // Per-wave static main-chunk descriptors (6 x 1KB chunks per wave)
    int cg[6], cl[6];
#pragma unroll
    for (int k = 0; k < 6; ++k) {
        int chunk = wv * 6 + k;          // 0..23
        int r = chunk >> 1, half = chunk & 1;
        int g = r >> 2, j = r & 3;
        cg[k] = refl(h + j + (g - 1) * DIL, HH) * WW + half * 256 + lane * 4;
        cl[k] = r * SEGP + DIL + half * 256 + lane * 4;
    }

    // Per-thread halo descriptors (reflected columns, <=2 per thread)
    int hs[NHAL], hd[NHAL];
    bool hv[NHAL];
#pragma unroll
    for (int m = 0; m < NHAL; ++m) {
        int u = tid + (m << 8);
        hv[m] = (u < 24 * DIL);
        int uu = hv[m] ? u : 0;
        int side = uu / (12 * DIL);
        int v = uu - side * 12 * DIL;
        int r = v / DIL, i = v - r * DIL;
        int g = r >> 2, j = r & 3;
        int ro = refl(h + j + (g - 1) * DIL, HH) * WW;
        hs[m] = ro + (side ? (510 - i) : (DIL - i));
        hd[m] = r * SEGP + (side ? (DIL + 512 + i) : i);
    }

#define STAGE(c, pb)                                                                      \
    {                                                                                     \
        const float* plane = base + (size_t)(c) * HWs;                                    \
        float* L = lds[pb];                                                               \
        _Pragma("unroll") for (int k = 0; k < 6; ++k)                                     \
            __builtin_amdgcn_global_load_lds(                                             \
                (const __attribute__((address_space(1))) void*)(plane + cg[k]),           \
                (__attribute__((address_space(3))) void*)(L + cl[k]), 16, 0, 0);          \
        _Pragma("unroll") for (int m = 0; m < NHAL; ++m)                                  \
            if (hv[m]) L[hd[m]] = plane[hs[m]];                                           \
    }

    STAGE(0, 0);
    __syncthreads();

    const float b0 = bias[2 * layer];
    const float b1 = bias[2 * layer + 1];
    float a[2][2][4];
#pragma unroll
    for (int p = 0; p < 2; ++p)
#pragma unroll
        for (int i = 0; i < 4; ++i) { a[p][0][i] = b0; a[p][1][i] = b1; }

    const int rowb0 = jbase * SEGP;
    const int rowb1 = (jbase + 2) * SEGP;

    for (int c = 0; c < NIN; ++c) {
        const int cur = c & 1;
        if (c + 1 < NIN) STAGE(c + 1, cur ^ 1);

        float wk0[9], wk1[9];
#pragma unroll
        for (int k = 0; k < 9; ++k) {
            wk0[k] = wts[c * 9 + k];
            wk1[k] = wts[(NIN + c) * 9 + k];
        }

        const float* L = lds[cur];
#pragma unroll
        for (int p = 0; p < 2; ++p) {
            const float* Lp = L + (p ? rowb1 : rowb0) + DIL + w0;
#pragma unroll
            for (int g = 0; g < 3; ++g) {
                const float* row = Lp + g * (4 * SEGP);
#pragma unroll
                for (int kw = 0; kw < 3; ++kw) {
                    const float* q = row + (kw - 1) * DIL;
                    const float wa = wk0[g * 3 + kw];
                    const float wb = wk1[g * 3 + kw];
#pragma unroll
                    for (int i = 0; i < 4; ++i) {
                        float v = q[i];
                        a[p][0][i] = fmaf(v, wa, a[p][0][i]);
                        a[p][1][i] = fmaf(v, wb, a[p][1][i]);
                    }
                }
            }
        }
        __syncthreads();
    }
#undef STAGE

    float* o0 = buf + (size_t)(b * NC + NIN) * HWs;
    float* o1 = buf + (size_t)(b * NC + NIN + 1) * HWs;
#pragma unroll
    for (int p = 0; p < 2; ++p) {
        int j = jbase + 2 * p;
        size_t off = (size_t)(h + j) * WW + (size_t)w0;
        float4 v0, v1;
        v0.x = fmaxf(a[p][0][0], 0.f); v0.y = fmaxf(a[p][0][1], 0.f);
        v0.z = fmaxf(a[p][0][2], 0.f); v0.w = fmaxf(a[p][0][3], 0.f);
        v1.x = fmaxf(a[p][1][0], 0.f); v1.y = fmaxf(a[p][1][1], 0.f);
        v1.z = fmaxf(a[p][1][2], 0.f); v1.w = fmaxf(a[p][1][3], 0.f);
        *(float4*)(o0 + off) = v0;
        *(float4*)(o1 + off) = v1;
    }
}

extern "C" void kernel_launch(void* const* d_in, const int* in_sizes, int n_in,
                              void* d_out, int out_size, void* d_ws, size_t ws_size,
                              hipStream_t stream) {
    const float* x = (const float*)d_in[0];
    const float* bias = (const float*)d_in[1];
    float* out = (float*)d_out;

    copy_x_kernel<<<1024, 256, 0, stream>>>(x, out);

    const int blocks = NB * (HH / 4);  // 512

#define LAYER(i, nin, dil) \
    msd_layer<nin, dil><<<blocks, 256, 0, stream>>>((const float*)d_in[2 + i], bias, out, i)

    LAYER(0, 1, 1);
    LAYER(1, 3, 2);
    LAYER(2, 5, 3);
    LAYER(3, 7, 4);
    LAYER(4, 9, 5);
    LAYER(5, 11, 6);
    LAYER(6, 13, 7);
    LAYER(7, 15, 8);
    LAYER(8, 17, 9);
    LAYER(9, 19, 10);
    LAYER(10, 21, 11);
    LAYER(11, 23, 12);
#undef LAYER
}